// Round 1
// baseline (1380.734 us; speedup 1.0000x reference)
//
#include <hip/hip_runtime.h>
#include <cstddef>
#include <cstdint>

// Problem: B=16, TQ=TP=DQ=DP=1024
//   pW = p @ W                     [B,TP,DQ]
//   S  = pW @ q^T  (per batch)     [B,TP,TQ]
//   w  = softmax(S, axis=TP)       (column-wise: normalizers per (b, q-col))
//   out= w @ q                     [B,TP,DQ]
//
// Workspace layout (floats): pW[16M] | S[16M] | m[16K] | rl[16K]  => ~128.3 MB

namespace {

constexpr int kB  = 16;
constexpr int kTQ = 1024;
constexpr int kTP = 1024;
constexpr int kDQ = 1024;
constexpr int kDP = 1024;

constexpr int BM = 128, BN = 128, BK = 16;

// ---------------------------------------------------------------------------
// K1: pW[M][N] = P[M][K] * W[K][N],  M = B*TP = 16384, N = DQ, K = DP  (NN)
// 256 threads, 8x8 per thread in split 4+4 layout (rows ty*4 / 64+ty*4).
// ---------------------------------------------------------------------------
__global__ __launch_bounds__(256) void k1_pw(const float* __restrict__ P,
                                             const float* __restrict__ W,
                                             float* __restrict__ pW) {
  __shared__ float As[BK][BM];  // [k][m]
  __shared__ float Bs[BK][BN];  // [k][n]
  const int tid = threadIdx.x;
  const int tx = tid & 15, ty = tid >> 4;
  const int m0 = blockIdx.y * BM, n0 = blockIdx.x * BN;
  const int arow = tid >> 2, akc = (tid & 3) << 2;  // A stage: 128 rows x 16 k
  const int bkr = tid >> 5, bnc = (tid & 31) << 2;  // B stage: 16 k x 128 n

  float acc[8][8];
#pragma unroll
  for (int r = 0; r < 8; ++r)
#pragma unroll
    for (int c = 0; c < 8; ++c) acc[r][c] = 0.f;

#pragma unroll 1
  for (int k0 = 0; k0 < kDP; k0 += BK) {
    float4 a0 = *(const float4*)(P + (size_t)(m0 + arow) * kDP + k0 + akc);
    float4 a1 = *(const float4*)(P + (size_t)(m0 + arow + 64) * kDP + k0 + akc);
    float4 b0 = *(const float4*)(W + (size_t)(k0 + bkr) * kDQ + n0 + bnc);
    float4 b1 = *(const float4*)(W + (size_t)(k0 + bkr + 8) * kDQ + n0 + bnc);
    __syncthreads();
    As[akc + 0][arow] = a0.x; As[akc + 1][arow] = a0.y;
    As[akc + 2][arow] = a0.z; As[akc + 3][arow] = a0.w;
    As[akc + 0][arow + 64] = a1.x; As[akc + 1][arow + 64] = a1.y;
    As[akc + 2][arow + 64] = a1.z; As[akc + 3][arow + 64] = a1.w;
    *(float4*)&Bs[bkr][bnc] = b0;
    *(float4*)&Bs[bkr + 8][bnc] = b1;
    __syncthreads();
#pragma unroll
    for (int kk = 0; kk < BK; ++kk) {
      const float4 av0 = *(const float4*)&As[kk][ty * 4];
      const float4 av1 = *(const float4*)&As[kk][64 + ty * 4];
      const float4 bv0 = *(const float4*)&Bs[kk][tx * 4];
      const float4 bv1 = *(const float4*)&Bs[kk][64 + tx * 4];
      const float am[8] = {av0.x, av0.y, av0.z, av0.w, av1.x, av1.y, av1.z, av1.w};
      const float bn_[8] = {bv0.x, bv0.y, bv0.z, bv0.w, bv1.x, bv1.y, bv1.z, bv1.w};
#pragma unroll
      for (int r = 0; r < 8; ++r)
#pragma unroll
        for (int c = 0; c < 8; ++c) acc[r][c] = fmaf(am[r], bn_[c], acc[r][c]);
    }
  }

#pragma unroll
  for (int r = 0; r < 8; ++r) {
    const int m = m0 + (r < 4 ? ty * 4 + r : 64 + ty * 4 + (r - 4));
    float4 v0 = make_float4(acc[r][0], acc[r][1], acc[r][2], acc[r][3]);
    float4 v1 = make_float4(acc[r][4], acc[r][5], acc[r][6], acc[r][7]);
    *(float4*)(pW + (size_t)m * kDQ + n0 + tx * 4) = v0;
    *(float4*)(pW + (size_t)m * kDQ + n0 + 64 + tx * 4) = v1;
  }
}

// ---------------------------------------------------------------------------
// K2: S[b][p][q] = sum_d pW[b][p][d] * Q[b][q][d]   (NT, per batch)
// ---------------------------------------------------------------------------
__global__ __launch_bounds__(256) void k2_scores(const float* __restrict__ pW,
                                                 const float* __restrict__ Q,
                                                 float* __restrict__ S) {
  __shared__ float As[BK][BM];
  __shared__ float Bs[BK][BN];
  const int b = blockIdx.z;
  const float* A  = pW + (size_t)b * kTP * kDQ;
  const float* Bq = Q + (size_t)b * kTQ * kDQ;
  float* Sb = S + (size_t)b * kTP * kTQ;

  const int tid = threadIdx.x;
  const int tx = tid & 15, ty = tid >> 4;
  const int m0 = blockIdx.y * BM, n0 = blockIdx.x * BN;
  const int arow = tid >> 2, akc = (tid & 3) << 2;

  float acc[8][8];
#pragma unroll
  for (int r = 0; r < 8; ++r)
#pragma unroll
    for (int c = 0; c < 8; ++c) acc[r][c] = 0.f;

#pragma unroll 1
  for (int k0 = 0; k0 < kDQ; k0 += BK) {
    float4 a0 = *(const float4*)(A + (size_t)(m0 + arow) * kDQ + k0 + akc);
    float4 a1 = *(const float4*)(A + (size_t)(m0 + arow + 64) * kDQ + k0 + akc);
    float4 b0 = *(const float4*)(Bq + (size_t)(n0 + arow) * kDQ + k0 + akc);
    float4 b1 = *(const float4*)(Bq + (size_t)(n0 + arow + 64) * kDQ + k0 + akc);
    __syncthreads();
    As[akc + 0][arow] = a0.x; As[akc + 1][arow] = a0.y;
    As[akc + 2][arow] = a0.z; As[akc + 3][arow] = a0.w;
    As[akc + 0][arow + 64] = a1.x; As[akc + 1][arow + 64] = a1.y;
    As[akc + 2][arow + 64] = a1.z; As[akc + 3][arow + 64] = a1.w;
    Bs[akc + 0][arow] = b0.x; Bs[akc + 1][arow] = b0.y;
    Bs[akc + 2][arow] = b0.z; Bs[akc + 3][arow] = b0.w;
    Bs[akc + 0][arow + 64] = b1.x; Bs[akc + 1][arow + 64] = b1.y;
    Bs[akc + 2][arow + 64] = b1.z; Bs[akc + 3][arow + 64] = b1.w;
    __syncthreads();
#pragma unroll
    for (int kk = 0; kk < BK; ++kk) {
      const float4 av0 = *(const float4*)&As[kk][ty * 4];
      const float4 av1 = *(const float4*)&As[kk][64 + ty * 4];
      const float4 bv0 = *(const float4*)&Bs[kk][tx * 4];
      const float4 bv1 = *(const float4*)&Bs[kk][64 + tx * 4];
      const float am[8] = {av0.x, av0.y, av0.z, av0.w, av1.x, av1.y, av1.z, av1.w};
      const float bn_[8] = {bv0.x, bv0.y, bv0.z, bv0.w, bv1.x, bv1.y, bv1.z, bv1.w};
#pragma unroll
      for (int r = 0; r < 8; ++r)
#pragma unroll
        for (int c = 0; c < 8; ++c) acc[r][c] = fmaf(am[r], bn_[c], acc[r][c]);
    }
  }

#pragma unroll
  for (int r = 0; r < 8; ++r) {
    const int m = m0 + (r < 4 ? ty * 4 + r : 64 + ty * 4 + (r - 4));
    float4 v0 = make_float4(acc[r][0], acc[r][1], acc[r][2], acc[r][3]);
    float4 v1 = make_float4(acc[r][4], acc[r][5], acc[r][6], acc[r][7]);
    *(float4*)(Sb + (size_t)m * kTQ + n0 + tx * 4) = v0;
    *(float4*)(Sb + (size_t)m * kTQ + n0 + 64 + tx * 4) = v1;
  }
}

// ---------------------------------------------------------------------------
// K3: column softmax stats. For each (b, q): m = max_p S[b][p][q],
//     rl = 1 / sum_p exp(S - m).  Online, one pass over S.
// Block: 256 threads = 8 row-groups x 32 columns. Grid: (TQ/32, B).
// ---------------------------------------------------------------------------
__global__ __launch_bounds__(256) void k3_stats(const float* __restrict__ S,
                                                float* __restrict__ mOut,
                                                float* __restrict__ rlOut) {
  const int b = blockIdx.y;
  const int q0 = blockIdx.x * 32;
  const int t = threadIdx.x;
  const int c = t & 31, g = t >> 5;
  const float* Sb = S + (size_t)b * kTP * kTQ + q0 + c;

  float m = -3.4e38f, l = 0.f;
#pragma unroll 4
  for (int p = g; p < kTP; p += 8) {
    const float x = Sb[(size_t)p * kTQ];
    if (x <= m) {
      l += __expf(x - m);
    } else {
      l = l * __expf(m - x) + 1.f;
      m = x;
    }
  }
  __shared__ float sm[8][32], sl[8][32];
  sm[g][c] = m;
  sl[g][c] = l;
  __syncthreads();
  if (t < 32) {
    float M = sm[0][t];
#pragma unroll
    for (int g2 = 1; g2 < 8; ++g2) M = fmaxf(M, sm[g2][t]);
    float L = 0.f;
#pragma unroll
    for (int g2 = 0; g2 < 8; ++g2) L += sl[g2][t] * __expf(sm[g2][t] - M);
    mOut[(size_t)b * kTQ + q0 + t] = M;
    rlOut[(size_t)b * kTQ + q0 + t] = 1.f / L;
  }
}

// ---------------------------------------------------------------------------
// K4: out[b][p][d] = sum_q (exp(S[b][p][q]-m[b][q])*rl[b][q]) * Q[b][q][d]
// NN GEMM per batch with the softmax transform fused into A-tile staging.
// ---------------------------------------------------------------------------
__global__ __launch_bounds__(256) void k4_out(const float* __restrict__ S,
                                              const float* __restrict__ mArr,
                                              const float* __restrict__ rlArr,
                                              const float* __restrict__ Q,
                                              float* __restrict__ Out) {
  __shared__ float As[BK][BM];
  __shared__ float Bs[BK][BN];
  const int b = blockIdx.z;
  const float* Sb = S + (size_t)b * kTP * kTQ;
  const float* Qb = Q + (size_t)b * kTQ * kDQ;
  const float* mB = mArr + (size_t)b * kTQ;
  const float* rB = rlArr + (size_t)b * kTQ;
  float* Ob = Out + (size_t)b * kTP * kDQ;

  const int tid = threadIdx.x;
  const int tx = tid & 15, ty = tid >> 4;
  const int m0 = blockIdx.y * BM, n0 = blockIdx.x * BN;
  const int arow = tid >> 2, akc = (tid & 3) << 2;
  const int bkr = tid >> 5, bnc = (tid & 31) << 2;

  float acc[8][8];
#pragma unroll
  for (int r = 0; r < 8; ++r)
#pragma unroll
    for (int c = 0; c < 8; ++c) acc[r][c] = 0.f;

#pragma unroll 1
  for (int k0 = 0; k0 < kTQ; k0 += BK) {
    float4 s0 = *(const float4*)(Sb + (size_t)(m0 + arow) * kTQ + k0 + akc);
    float4 s1 = *(const float4*)(Sb + (size_t)(m0 + arow + 64) * kTQ + k0 + akc);
    const float4 mm = *(const float4*)(mB + k0 + akc);
    const float4 rr = *(const float4*)(rB + k0 + akc);
    float4 b0 = *(const float4*)(Qb + (size_t)(k0 + bkr) * kDQ + n0 + bnc);
    float4 b1 = *(const float4*)(Qb + (size_t)(k0 + bkr + 8) * kDQ + n0 + bnc);
    __syncthreads();
    As[akc + 0][arow] = __expf(s0.x - mm.x) * rr.x;
    As[akc + 1][arow] = __expf(s0.y - mm.y) * rr.y;
    As[akc + 2][arow] = __expf(s0.z - mm.z) * rr.z;
    As[akc + 3][arow] = __expf(s0.w - mm.w) * rr.w;
    As[akc + 0][arow + 64] = __expf(s1.x - mm.x) * rr.x;
    As[akc + 1][arow + 64] = __expf(s1.y - mm.y) * rr.y;
    As[akc + 2][arow + 64] = __expf(s1.z - mm.z) * rr.z;
    As[akc + 3][arow + 64] = __expf(s1.w - mm.w) * rr.w;
    *(float4*)&Bs[bkr][bnc] = b0;
    *(float4*)&Bs[bkr + 8][bnc] = b1;
    __syncthreads();
#pragma unroll
    for (int kk = 0; kk < BK; ++kk) {
      const float4 av0 = *(const float4*)&As[kk][ty * 4];
      const float4 av1 = *(const float4*)&As[kk][64 + ty * 4];
      const float4 bv0 = *(const float4*)&Bs[kk][tx * 4];
      const float4 bv1 = *(const float4*)&Bs[kk][64 + tx * 4];
      const float am[8] = {av0.x, av0.y, av0.z, av0.w, av1.x, av1.y, av1.z, av1.w};
      const float bn_[8] = {bv0.x, bv0.y, bv0.z, bv0.w, bv1.x, bv1.y, bv1.z, bv1.w};
#pragma unroll
      for (int r = 0; r < 8; ++r)
#pragma unroll
        for (int c = 0; c < 8; ++c) acc[r][c] = fmaf(am[r], bn_[c], acc[r][c]);
    }
  }

#pragma unroll
  for (int r = 0; r < 8; ++r) {
    const int m = m0 + (r < 4 ? ty * 4 + r : 64 + ty * 4 + (r - 4));
    float4 v0 = make_float4(acc[r][0], acc[r][1], acc[r][2], acc[r][3]);
    float4 v1 = make_float4(acc[r][4], acc[r][5], acc[r][6], acc[r][7]);
    *(float4*)(Ob + (size_t)m * kDQ + n0 + tx * 4) = v0;
    *(float4*)(Ob + (size_t)m * kDQ + n0 + 64 + tx * 4) = v1;
  }
}

}  // namespace

extern "C" void kernel_launch(void* const* d_in, const int* in_sizes, int n_in,
                              void* d_out, int out_size, void* d_ws, size_t ws_size,
                              hipStream_t stream) {
  const float* q = (const float*)d_in[0];  // [B, TQ, DQ]
  const float* p = (const float*)d_in[1];  // [B, TP, DP]
  const float* W = (const float*)d_in[2];  // [DP, DQ]
  float* out = (float*)d_out;              // [B, TP, DQ]

  float* ws = (float*)d_ws;
  float* pW   = ws;                                    // 16M floats
  float* S    = pW + (size_t)kB * kTP * kDQ;           // 16M floats
  float* mArr = S + (size_t)kB * kTP * kTQ;            // 16K floats
  float* rlArr = mArr + (size_t)kB * kTQ;              // 16K floats

  const dim3 blk(256);
  k1_pw<<<dim3(kDQ / BN, (kB * kTP) / BM), blk, 0, stream>>>(p, W, pW);
  k2_scores<<<dim3(kTQ / BN, kTP / BM, kB), blk, 0, stream>>>(pW, q, S);
  k3_stats<<<dim3(kTQ / 32, kB), blk, 0, stream>>>(S, mArr, rlArr);
  k4_out<<<dim3(kDQ / BN, kTP / BM, kB), blk, 0, stream>>>(S, mArr, rlArr, q, out);
}

// Round 2
// 613.331 us; speedup vs baseline: 2.2512x; 2.2512x over previous
//
#include <hip/hip_runtime.h>
#include <cstddef>
#include <cstdint>

// B=16, TQ=TP=DQ=DP=1024.
//   pW = p @ W ; S = pW @ q^T ; w = softmax(S, axis=TP) ; out = w @ q
// All three GEMMs run as bf16x3 split-precision MFMA (hi+lo bf16 per f32,
// terms hh + lh + hl), f32 accumulation -> ~f32 accuracy at ~bf16/3 rate.
//
// Workspace (128.13 MB, same as proven round-1 budget):
//   [0,64MB)    : pW_hi|pW_lo (g1->g2), later REUSED as qT_hi|qT_lo (conv_qt->g4)
//   [64,128MB)  : S (f32); its first 4MB holds WT_hi|WT_lo during conv_w/g1 only
//   [128MB,+128KB): m, rl stats

namespace {

using u16 = unsigned short;
using frag  = __attribute__((ext_vector_type(8))) short;  // 8 bf16 = 4 VGPR
using f32x4 = __attribute__((ext_vector_type(4))) float;

constexpr int kB = 16;
constexpr int kT = 1024;   // TQ = TP
constexpr int kD = 1024;   // DQ = DP
constexpr int BM = 128, BN = 128, BK = 32;
constexpr int KSTEPS = kD / BK;

union FragU { frag v; u16 u[8]; };

__device__ __forceinline__ u16 f2bf(float x) {  // RNE f32->bf16
  uint32_t u = __float_as_uint(x);
  return (u16)((u + 0x7FFFu + ((u >> 16) & 1u)) >> 16);
}
__device__ __forceinline__ float bf2f(u16 h) {
  return __uint_as_float(((uint32_t)h) << 16);
}

#define AS1(p) (const __attribute__((address_space(1))) void*)(p)
#define AS3(p) (__attribute__((address_space(3))) void*)(p)

__device__ __forceinline__ void gl_lds16(const u16* g, u16* l) {
  __builtin_amdgcn_global_load_lds(AS1(g), AS3(l), 16, 0, 0);
}

// Fill lds[128][32] u16 tile from pre-split row-major src (stride 1024 u16).
// Linear LDS dest (wave-uniform base + lane*16B), per-lane global src.
__device__ __forceinline__ void stage_glds(const u16* __restrict__ src, u16* lds,
                                           int row0, int k0, int tid) {
  const int w = tid >> 6, l = tid & 63;
#pragma unroll
  for (int rr = 0; rr < 2; ++rr) {
    const int chunk = rr * 4 + w;                 // 8 chunks of 16 rows
    const int row = chunk * 16 + (l >> 2);
    const int kc = (l & 3) * 8;
    gl_lds16(src + (size_t)(row0 + row) * 1024 + k0 + kc, lds + chunk * 512);
  }
}

struct Reg16 { float4 v[4]; };

__device__ __forceinline__ Reg16 load_tile16(const float* __restrict__ src,
                                             int row0, int k0, int tid) {
  const int r = tid >> 1, c0 = (tid & 1) << 4;
  const float4* g = (const float4*)(src + (size_t)(row0 + r) * 1024 + k0 + c0);
  Reg16 out;
#pragma unroll
  for (int i = 0; i < 4; ++i) out.v[i] = g[i];
  return out;
}

__device__ __forceinline__ void write_split(const Reg16& rg, u16* ldsHi, u16* ldsLo,
                                            int tid) {
  const int r = tid >> 1, c0 = (tid & 1) << 4;
  float vv[16];
#pragma unroll
  for (int i = 0; i < 4; ++i) {
    vv[4*i+0] = rg.v[i].x; vv[4*i+1] = rg.v[i].y;
    vv[4*i+2] = rg.v[i].z; vv[4*i+3] = rg.v[i].w;
  }
  FragU h0, l0, h1, l1;
#pragma unroll
  for (int i = 0; i < 8; ++i) {
    u16 h = f2bf(vv[i]);     h0.u[i] = h; l0.u[i] = f2bf(vv[i]     - bf2f(h));
  }
#pragma unroll
  for (int i = 0; i < 8; ++i) {
    u16 h = f2bf(vv[8+i]);   h1.u[i] = h; l1.u[i] = f2bf(vv[8+i]   - bf2f(h));
  }
  *(frag*)(ldsHi + r*32 + c0)     = h0.v;
  *(frag*)(ldsHi + r*32 + c0 + 8) = h1.v;
  *(frag*)(ldsLo + r*32 + c0)     = l0.v;
  *(frag*)(ldsLo + r*32 + c0 + 8) = l1.v;
}

__device__ __forceinline__ void write_split_exp(const Reg16& rg, const float* mL,
                                                const float* rL, u16* ldsHi,
                                                u16* ldsLo, int k0, int tid) {
  const int r = tid >> 1, c0 = (tid & 1) << 4;
  float vv[16];
#pragma unroll
  for (int i = 0; i < 4; ++i) {
    vv[4*i+0] = rg.v[i].x; vv[4*i+1] = rg.v[i].y;
    vv[4*i+2] = rg.v[i].z; vv[4*i+3] = rg.v[i].w;
  }
#pragma unroll
  for (int i = 0; i < 16; ++i) {
    const int k = k0 + c0 + i;
    vv[i] = __expf(vv[i] - mL[k]) * rL[k];
  }
  FragU h0, l0, h1, l1;
#pragma unroll
  for (int i = 0; i < 8; ++i) {
    u16 h = f2bf(vv[i]);   h0.u[i] = h; l0.u[i] = f2bf(vv[i]   - bf2f(h));
  }
#pragma unroll
  for (int i = 0; i < 8; ++i) {
    u16 h = f2bf(vv[8+i]); h1.u[i] = h; l1.u[i] = f2bf(vv[8+i] - bf2f(h));
  }
  *(frag*)(ldsHi + r*32 + c0)     = h0.v;
  *(frag*)(ldsHi + r*32 + c0 + 8) = h1.v;
  *(frag*)(ldsLo + r*32 + c0)     = l0.v;
  *(frag*)(ldsLo + r*32 + c0 + 8) = l1.v;
}

// 3-term MFMA over one K-step. A tile [128][32], B^T tile [128][32].
__device__ __forceinline__ void compute_step(const u16* AhS, const u16* AlS,
                                             const u16* BhS, const u16* BlS,
                                             f32x4 acc[4][4], int lane, int wr, int wc) {
  const int kb = (lane >> 4) * 8;   // 8 bf16 along K per lane
  const int ra = lane & 15;
  frag ah[4], al[4];
#pragma unroll
  for (int m = 0; m < 4; ++m) {
    const int row = wr*64 + m*16 + ra;
    ah[m] = *(const frag*)(AhS + row*32 + kb);
    al[m] = *(const frag*)(AlS + row*32 + kb);
  }
#pragma unroll
  for (int n = 0; n < 4; ++n) {
    const int col = wc*64 + n*16 + ra;
    const frag bh = *(const frag*)(BhS + col*32 + kb);
    const frag bl = *(const frag*)(BlS + col*32 + kb);
#pragma unroll
    for (int m = 0; m < 4; ++m) {
      acc[m][n] = __builtin_amdgcn_mfma_f32_16x16x32_bf16(ah[m], bh, acc[m][n], 0, 0, 0);
      acc[m][n] = __builtin_amdgcn_mfma_f32_16x16x32_bf16(al[m], bh, acc[m][n], 0, 0, 0);
      acc[m][n] = __builtin_amdgcn_mfma_f32_16x16x32_bf16(ah[m], bl, acc[m][n], 0, 0, 0);
    }
  }
}

// C/D layout (verified m89/m91): col = lane&15, row = (lane>>4)*4 + reg.
__device__ __forceinline__ void epilogue_f32(float* __restrict__ dst, f32x4 acc[4][4],
                                             int row0, int col0, int lane, int wr, int wc) {
#pragma unroll
  for (int m = 0; m < 4; ++m)
#pragma unroll
    for (int n = 0; n < 4; ++n) {
      const int col = col0 + wc*64 + n*16 + (lane & 15);
      const int rb  = row0 + wr*64 + m*16 + ((lane >> 4) << 2);
#pragma unroll
      for (int j = 0; j < 4; ++j)
        dst[(size_t)(rb + j) * 1024 + col] = acc[m][n][j];
    }
}

// ---------------------------------------------------------------------------
// g1: pW = p @ WT^T.  A = p (f32 reg-staged+split), B = WT hi/lo (glds).
// Writes pW as split hi/lo bf16.
// ---------------------------------------------------------------------------
__global__ __launch_bounds__(256) void g1_pw(const float* __restrict__ P,
                                             const u16* __restrict__ WTh,
                                             const u16* __restrict__ WTl,
                                             u16* __restrict__ pWh,
                                             u16* __restrict__ pWl) {
  __shared__ u16 AhS[BM*BK], AlS[BM*BK], BhS[BN*BK], BlS[BN*BK];
  const int tid = threadIdx.x, lane = tid & 63;
  const int wid = tid >> 6, wr = wid >> 1, wc = wid & 1;
  const int m0 = blockIdx.y * BM, n0 = blockIdx.x * BN;

  f32x4 acc[4][4];
#pragma unroll
  for (int m = 0; m < 4; ++m)
#pragma unroll
    for (int n = 0; n < 4; ++n) acc[m][n] = (f32x4){0.f, 0.f, 0.f, 0.f};

  Reg16 a = load_tile16(P, m0, 0, tid);
#pragma unroll 1
  for (int ks = 0; ks < KSTEPS; ++ks) {
    const int k0 = ks * BK;
    __syncthreads();
    stage_glds(WTh, BhS, n0, k0, tid);
    stage_glds(WTl, BlS, n0, k0, tid);
    write_split(a, AhS, AlS, tid);
    if (ks + 1 < KSTEPS) a = load_tile16(P, m0, k0 + BK, tid);
    __syncthreads();
    compute_step(AhS, AlS, BhS, BlS, acc, lane, wr, wc);
  }

#pragma unroll
  for (int m = 0; m < 4; ++m)
#pragma unroll
    for (int n = 0; n < 4; ++n) {
      const int col = n0 + wc*64 + n*16 + (lane & 15);
      const int rb  = m0 + wr*64 + m*16 + ((lane >> 4) << 2);
#pragma unroll
      for (int j = 0; j < 4; ++j) {
        const float x = acc[m][n][j];
        const u16 h = f2bf(x);
        pWh[(size_t)(rb + j) * 1024 + col] = h;
        pWl[(size_t)(rb + j) * 1024 + col] = f2bf(x - bf2f(h));
      }
    }
}

// ---------------------------------------------------------------------------
// g2: S[b] = pW[b] @ q[b]^T.  A = pW hi/lo (glds), B = q (f32 reg-staged).
// ---------------------------------------------------------------------------
__global__ __launch_bounds__(256) void g2_scores(const u16* __restrict__ pWh,
                                                 const u16* __restrict__ pWl,
                                                 const float* __restrict__ Q,
                                                 float* __restrict__ S) {
  __shared__ u16 AhS[BM*BK], AlS[BM*BK], BhS[BN*BK], BlS[BN*BK];
  const int tid = threadIdx.x, lane = tid & 63;
  const int wid = tid >> 6, wr = wid >> 1, wc = wid & 1;
  const int b = blockIdx.z;
  const int m0 = blockIdx.y * BM, n0 = blockIdx.x * BN;
  const int rowA0 = b * kT + m0;                 // pW is flat [16384][1024]
  const float* Qb = Q + (size_t)b * kT * kD;
  float* Sb = S + (size_t)b * kT * kT;

  f32x4 acc[4][4];
#pragma unroll
  for (int m = 0; m < 4; ++m)
#pragma unroll
    for (int n = 0; n < 4; ++n) acc[m][n] = (f32x4){0.f, 0.f, 0.f, 0.f};

  Reg16 bq = load_tile16(Qb, n0, 0, tid);
#pragma unroll 1
  for (int ks = 0; ks < KSTEPS; ++ks) {
    const int k0 = ks * BK;
    __syncthreads();
    stage_glds(pWh, AhS, rowA0, k0, tid);
    stage_glds(pWl, AlS, rowA0, k0, tid);
    write_split(bq, BhS, BlS, tid);
    if (ks + 1 < KSTEPS) bq = load_tile16(Qb, n0, k0 + BK, tid);
    __syncthreads();
    compute_step(AhS, AlS, BhS, BlS, acc, lane, wr, wc);
  }
  epilogue_f32(Sb, acc, m0, n0, lane, wr, wc);
}

// ---------------------------------------------------------------------------
// k3: column softmax stats over TP. m[b][q], rl[b][q] = 1/sumexp.
// ---------------------------------------------------------------------------
__global__ __launch_bounds__(256) void k3_stats(const float* __restrict__ S,
                                                float* __restrict__ mOut,
                                                float* __restrict__ rlOut) {
  const int b = blockIdx.y;
  const int q0 = blockIdx.x * 32;
  const int t = threadIdx.x;
  const int c = t & 31, g = t >> 5;
  const float* Sb = S + (size_t)b * kT * kT + q0 + c;

  float m = -3.4e38f, l = 0.f;
#pragma unroll 4
  for (int p = g; p < kT; p += 8) {
    const float x = Sb[(size_t)p * kT];
    if (x <= m) {
      l += __expf(x - m);
    } else {
      l = l * __expf(m - x) + 1.f;
      m = x;
    }
  }
  __shared__ float sm[8][32], sl[8][32];
  sm[g][c] = m;
  sl[g][c] = l;
  __syncthreads();
  if (t < 32) {
    float M = sm[0][t];
#pragma unroll
    for (int g2 = 1; g2 < 8; ++g2) M = fmaxf(M, sm[g2][t]);
    float L = 0.f;
#pragma unroll
    for (int g2 = 0; g2 < 8; ++g2) L += sl[g2][t] * __expf(sm[g2][t] - M);
    mOut[(size_t)b * kT + q0 + t] = M;
    rlOut[(size_t)b * kT + q0 + t] = 1.f / L;
  }
}

// ---------------------------------------------------------------------------
// conv_t_split: transpose + hi/lo split. dst[j][i] = split(src[i][j]).
// Used for W (gridz=1) and for q -> qT per batch (gridz=16).
// ---------------------------------------------------------------------------
__global__ __launch_bounds__(256) void conv_t_split(const float* __restrict__ src,
                                                    u16* __restrict__ dstH,
                                                    u16* __restrict__ dstL) {
  __shared__ float ts[64][65];
  const size_t boff = (size_t)blockIdx.z * kT * kD;
  const int t = threadIdx.x;
  const int i0 = blockIdx.y * 64, j0 = blockIdx.x * 64;
  const int r = t >> 2, c0 = (t & 3) << 4;
  const float4* g = (const float4*)(src + boff + (size_t)(i0 + r) * 1024 + j0 + c0);
#pragma unroll
  for (int i = 0; i < 4; ++i) {
    const float4 v = g[i];
    ts[r][c0 + 4*i + 0] = v.x; ts[r][c0 + 4*i + 1] = v.y;
    ts[r][c0 + 4*i + 2] = v.z; ts[r][c0 + 4*i + 3] = v.w;
  }
  __syncthreads();
  FragU h0, l0, h1, l1;
#pragma unroll
  for (int i = 0; i < 8; ++i) {
    const float x = ts[c0 + i][r];
    const u16 h = f2bf(x); h0.u[i] = h; l0.u[i] = f2bf(x - bf2f(h));
  }
#pragma unroll
  for (int i = 0; i < 8; ++i) {
    const float x = ts[c0 + 8 + i][r];
    const u16 h = f2bf(x); h1.u[i] = h; l1.u[i] = f2bf(x - bf2f(h));
  }
  u16* dh = dstH + boff + (size_t)(j0 + r) * 1024 + i0 + c0;
  u16* dl = dstL + boff + (size_t)(j0 + r) * 1024 + i0 + c0;
  *(frag*)dh = h0.v; *((frag*)dh + 1) = h1.v;
  *(frag*)dl = l0.v; *((frag*)dl + 1) = l1.v;
}

// ---------------------------------------------------------------------------
// g4: out[b] = softmax-weights @ q[b].  A = S (f32 reg-staged, exp fused,
// split), B = qT hi/lo (glds).
// ---------------------------------------------------------------------------
__global__ __launch_bounds__(256) void g4_out(const float* __restrict__ S,
                                              const float* __restrict__ mArr,
                                              const float* __restrict__ rlArr,
                                              const u16* __restrict__ qTh,
                                              const u16* __restrict__ qTl,
                                              float* __restrict__ Out) {
  __shared__ u16 AhS[BM*BK], AlS[BM*BK], BhS[BN*BK], BlS[BN*BK];
  __shared__ float mL[kT], rL[kT];
  const int tid = threadIdx.x, lane = tid & 63;
  const int wid = tid >> 6, wr = wid >> 1, wc = wid & 1;
  const int b = blockIdx.z;
  const int m0 = blockIdx.y * BM, n0 = blockIdx.x * BN;
  const float* Sb = S + (size_t)b * kT * kT;
  const u16* qThb = qTh + (size_t)b * kT * kD;
  const u16* qTlb = qTl + (size_t)b * kT * kD;
  float* Ob = Out + (size_t)b * kT * kD;

  for (int i = tid; i < kT; i += 256) {
    mL[i] = mArr[(size_t)b * kT + i];
    rL[i] = rlArr[(size_t)b * kT + i];
  }

  f32x4 acc[4][4];
#pragma unroll
  for (int m = 0; m < 4; ++m)
#pragma unroll
    for (int n = 0; n < 4; ++n) acc[m][n] = (f32x4){0.f, 0.f, 0.f, 0.f};

  Reg16 a = load_tile16(Sb, m0, 0, tid);
#pragma unroll 1
  for (int ks = 0; ks < KSTEPS; ++ks) {
    const int k0 = ks * BK;
    __syncthreads();
    stage_glds(qThb, BhS, n0, k0, tid);
    stage_glds(qTlb, BlS, n0, k0, tid);
    write_split_exp(a, mL, rL, AhS, AlS, k0, tid);
    if (ks + 1 < KSTEPS) a = load_tile16(Sb, m0, k0 + BK, tid);
    __syncthreads();
    compute_step(AhS, AlS, BhS, BlS, acc, lane, wr, wc);
  }
  epilogue_f32(Ob, acc, m0, n0, lane, wr, wc);
}

}  // namespace

extern "C" void kernel_launch(void* const* d_in, const int* in_sizes, int n_in,
                              void* d_out, int out_size, void* d_ws, size_t ws_size,
                              hipStream_t stream) {
  const float* q = (const float*)d_in[0];  // [B, TQ, DQ]
  const float* p = (const float*)d_in[1];  // [B, TP, DP]
  const float* W = (const float*)d_in[2];  // [DP, DQ]
  float* out = (float*)d_out;              // [B, TP, DQ]

  char* wsb = (char*)d_ws;
  u16* pWh = (u16*)wsb;                               // 32MB
  u16* pWl = (u16*)(wsb + (32ull << 20));             // 32MB
  u16* qTh = pWh;                                     // alias (pW dead after g2)
  u16* qTl = pWl;
  float* S   = (float*)(wsb + (64ull << 20));         // 64MB
  u16* WTh = (u16*)(wsb + (64ull << 20));             // 2MB, dead before S written
  u16* WTl = (u16*)(wsb + (64ull << 20) + (2ull << 20));
  float* mArr  = (float*)(wsb + (128ull << 20));      // 64KB
  float* rlArr = mArr + (size_t)kB * kT;              // 64KB

  const dim3 blk(256);
  conv_t_split<<<dim3(16, 16, 1), blk, 0, stream>>>(W, WTh, WTl);
  g1_pw<<<dim3(kD / BN, (kB * kT) / BM), blk, 0, stream>>>(p, WTh, WTl, pWh, pWl);
  g2_scores<<<dim3(kT / BN, kT / BM, kB), blk, 0, stream>>>(pWh, pWl, q, S);
  k3_stats<<<dim3(kT / 32, kB), blk, 0, stream>>>(S, mArr, rlArr);
  conv_t_split<<<dim3(16, 16, kB), blk, 0, stream>>>(q, qTh, qTl);
  g4_out<<<dim3(kD / BN, kT / BM, kB), blk, 0, stream>>>(S, mArr, rlArr, qTh, qTl, out);
}